// Round 12
// baseline (2177.886 us; speedup 1.0000x reference)
//
#include <hip/hip_runtime.h>

// TwoStreamNet on MI355X — f32 I/O, bf16 MFMA internals.
// R12: new counted-vmcnt pipelined GEMM (gemm8_k) for the big adjacency GEMMs:
//      128x256x64 tile, 8 waves, 3-slot LDS ring (144KB), T2 xor-swizzle
//      (inverse-swizzled global source + swizzled ds_read), steady-state
//      s_waitcnt vmcnt(12) with raw s_barrier (no drain), setprio around MFMA.
//      Weight/PDF GEMMs and all other kernels unchanged from R11.

typedef short short8 __attribute__((ext_vector_type(8)));
typedef float floatx4 __attribute__((ext_vector_type(4)));
typedef unsigned short ushort4v __attribute__((ext_vector_type(4)));
typedef unsigned short u16;

#define DIMN 256
#define GBK 64

static const int kNV = 6144;
static const int kNF = 12288;
static const int SLAB = 768;

__device__ __forceinline__ float bf2f(u16 u) {
  union { unsigned int i; float f; } x; x.i = ((unsigned int)u) << 16; return x.f;
}
__device__ __forceinline__ u16 f2bf(float f) {
  union { float f; unsigned int i; } x; x.f = f;
  unsigned int r = x.i + 0x7fffu + ((x.i >> 16) & 1u);
  return (u16)(r >> 16);
}
__device__ __forceinline__ void gld_lds16(const void* g, void* l) {
  __builtin_amdgcn_global_load_lds((__attribute__((address_space(1))) void*)(g),
                                   (__attribute__((address_space(3))) void*)(l),
                                   16, 0, 0);
}

// ============ gemm8_k: pipelined partial GEMM, A/B bf16 only =======================
// C_partial[bz] = A[M][K]-chunk x Bt[256][K]^T.  BM=128, BN=256, BK=64.
// 512 threads = 8 waves (wr=wid>>2 in 0..1 -> 64 rows; wc=wid&3 -> 64 cols).
// LDS: 3-slot ring, tile = A 128x64 (16KB) + B 256x64 (32KB).
// Staging: per wave 2 A-chunks + 4 B-chunks (1KB each: 8 rows x 128B); source col
// pre-swizzled by ((lane&7)^(lane>>3)) so linear LDS holds the swizzled layout.
// Reads: frag col-group c8 ^ (row&7) -> 8 distinct 16B bank slots (conflict-free).
// Pipeline: prefetch 2 tiles ahead; steady-state s_waitcnt vmcnt(12); raw barriers.
__global__ __launch_bounds__(512, 1)
void gemm8_k(const u16* __restrict__ A, int lda,
             const u16* __restrict__ Bt, int ldb,
             u16* __restrict__ P, int M, int nx, int kchunk)
{
  __shared__ __align__(16) u16 As[3][128 * 64];   // 3 x 16 KB
  __shared__ __align__(16) u16 Bs[3][256 * 64];   // 3 x 32 KB  (total 144 KB)

  const int d = blockIdx.x;
  const int bx = d % nx;
  const int bz = d / nx;
  const int m0 = bx << 7;
  const int kb = bz * kchunk;
  const int nkt = kchunk >> 6;

  const int tid = threadIdx.x;
  const int wid = tid >> 6, lane = tid & 63;
  const int wr = wid >> 2, wc = wid & 3;
  const int srow = lane >> 3;                     // 0..7 row within 1KB chunk
  const int scol = ((lane & 7) ^ srow) << 3;      // inverse-swizzled source col

  floatx4 acc[4][4];
  floatx4 zz = {0.f, 0.f, 0.f, 0.f};
#pragma unroll
  for (int i = 0; i < 4; ++i)
#pragma unroll
    for (int j = 0; j < 4; ++j) acc[i][j] = zz;

  auto stage = [&](int slot, int k0) {
#pragma unroll
    for (int j = 0; j < 2; ++j) {                 // A: 16 chunks, 2/wave
      int c = (wid << 1) + j;
      gld_lds16(A + (size_t)(m0 + (c << 3) + srow) * lda + k0 + scol,
                (void*)&As[slot][c << 9]);
    }
#pragma unroll
    for (int j = 0; j < 4; ++j) {                 // B: 32 chunks, 4/wave
      int c = (wid << 2) + j;
      gld_lds16(Bt + (size_t)((c << 3) + srow) * ldb + k0 + scol,
                (void*)&Bs[slot][c << 9]);
    }
  };

  stage(0, kb);
  if (nkt > 1) stage(1, kb + GBK);

  int cur = 0;
  for (int t = 0; t < nkt; ++t) {
    if (t + 2 < nkt) stage((cur + 2) % 3, kb + (t + 2) * GBK);
    if (t + 2 < nkt)      asm volatile("s_waitcnt vmcnt(12)" ::: "memory");
    else if (t + 1 < nkt) asm volatile("s_waitcnt vmcnt(6)" ::: "memory");
    else                  asm volatile("s_waitcnt vmcnt(0)" ::: "memory");
    __builtin_amdgcn_s_barrier();   // writes of tile t visible to all waves

    short8 a[4][2], b[4][2];
#pragma unroll
    for (int mf = 0; mf < 4; ++mf)
#pragma unroll
      for (int ks = 0; ks < 2; ++ks) {
        const int row = (wr << 6) + (mf << 4) + (lane & 15);
        const int c8 = ((ks << 2) + (lane >> 4)) ^ (row & 7);
        a[mf][ks] = *(const short8*)&As[cur][row * 64 + (c8 << 3)];
      }
#pragma unroll
    for (int nf = 0; nf < 4; ++nf)
#pragma unroll
      for (int ks = 0; ks < 2; ++ks) {
        const int row = (wc << 6) + (nf << 4) + (lane & 15);
        const int c8 = ((ks << 2) + (lane >> 4)) ^ (row & 7);
        b[nf][ks] = *(const short8*)&Bs[cur][row * 64 + (c8 << 3)];
      }
    __builtin_amdgcn_s_setprio(1);
#pragma unroll
    for (int ks = 0; ks < 2; ++ks)
#pragma unroll
      for (int mf = 0; mf < 4; ++mf)
#pragma unroll
        for (int nf = 0; nf < 4; ++nf)
          acc[mf][nf] = __builtin_amdgcn_mfma_f32_16x16x32_bf16(
              a[mf][ks], b[nf][ks], acc[mf][nf], 0, 0, 0);
    __builtin_amdgcn_s_setprio(0);
    __builtin_amdgcn_s_barrier();   // all waves done reading slot cur
    cur = (cur + 1) % 3;
  }

  u16* Pz = P + (size_t)bz * (size_t)M * DIMN;
#pragma unroll
  for (int mf = 0; mf < 4; ++mf) {
#pragma unroll
    for (int nf = 0; nf < 4; ++nf) {
      const int mb = m0 + (wr << 6) + (mf << 4) + ((lane >> 4) << 2);
      const int n = (wc << 6) + (nf << 4) + (lane & 15);
#pragma unroll
      for (int r = 0; r < 4; ++r)
        Pz[(size_t)(mb + r) * DIMN + n] = f2bf(acc[mf][nf][r]);
    }
  }
}

// ---------------- legacy GEMM (weight/PDF/fallback): C = Aop x Bt^T -----------------
// 256 threads = 4 waves (2x2), 128x128 tile. A segments A0/A1 split at K1; mode:
// 0 = bf16 gld_lds, 1 = f32 reg-convert. fused=0: bf16 partials; fused=1: epilogue
// (bias, addmat bf16, relu, resid f32) -> outf/out16/outT (transposed via LDS).
__global__ __launch_bounds__(256, 2)
void gemm_bf16_k(const void* __restrict__ A0, int A0mode, int lda0,
                 const void* __restrict__ A1, int A1mode, int lda1, int K1,
                 const void* __restrict__ Bt, int Btis32, int ldb,
                 u16* __restrict__ P, int M, int nx, int kchunk,
                 int fused, const float* __restrict__ bias,
                 const u16* __restrict__ addmat, int do_relu,
                 const float* __restrict__ resid,
                 float* __restrict__ outf, u16* __restrict__ out16,
                 u16* __restrict__ outT)
{
  __shared__ __align__(16) u16 As[2][128 * GBK];
  __shared__ __align__(16) u16 Bs[2][128 * GBK];

  const int d = blockIdx.x;
  const int y = d & 1;
  const int bx = (d >> 1) % nx;
  const int bz = (d >> 1) / nx;
  const int m0 = bx << 7;
  const int n0 = y << 7;
  const int kb = bz * kchunk;
  const int nkt = kchunk / GBK;

  const int tid = threadIdx.x;
  const int wid = tid >> 6;
  const int lane = tid & 63;
  const int wr = wid >> 1, wc = wid & 1;
  const int srow = lane >> 3;
  const int skk = (lane & 7) << 3;

  floatx4 acc[4][4];
  floatx4 zz = {0.f, 0.f, 0.f, 0.f};
#pragma unroll
  for (int i = 0; i < 4; ++i)
#pragma unroll
    for (int j = 0; j < 4; ++j) acc[i][j] = zz;

  auto stage = [&](int buf, int k0) {
    const void* base; int lda, mode, kl;
    if (k0 < K1) { base = A0; lda = lda0; mode = A0mode; kl = k0; }
    else         { base = A1; lda = lda1; mode = A1mode; kl = k0 - K1; }
    if (mode == 0) {
      const u16* U = (const u16*)base;
#pragma unroll
      for (int j = 0; j < 4; ++j) {
        int c = (wid << 2) + j;
        gld_lds16(U + (size_t)(m0 + (c << 3) + srow) * lda + kl + skk,
                  (void*)&As[buf][c << 9]);
      }
    } else {
      const float* F = (const float*)base;
#pragma unroll
      for (int j = 0; j < 4; ++j) {
        int c = (wid << 2) + j;
        const size_t gi = (size_t)(m0 + (c << 3) + srow) * lda + kl + skk;
        floatx4 f0 = *(const floatx4*)(F + gi);
        floatx4 f1 = *(const floatx4*)(F + gi + 4);
        short8 v;
#pragma unroll
        for (int e = 0; e < 4; ++e) { v[e] = (short)f2bf(f0[e]); v[4 + e] = (short)f2bf(f1[e]); }
        *(short8*)&As[buf][(c << 9) + (lane << 3)] = v;
      }
    }
    if (Btis32) {
      const float* F = (const float*)Bt;
#pragma unroll
      for (int j = 0; j < 4; ++j) {
        int c = (wid << 2) + j;
        const size_t gi = (size_t)(n0 + (c << 3) + srow) * ldb + k0 + skk;
        floatx4 f0 = *(const floatx4*)(F + gi);
        floatx4 f1 = *(const floatx4*)(F + gi + 4);
        short8 v;
#pragma unroll
        for (int e = 0; e < 4; ++e) { v[e] = (short)f2bf(f0[e]); v[4 + e] = (short)f2bf(f1[e]); }
        *(short8*)&Bs[buf][(c << 9) + (lane << 3)] = v;
      }
    } else {
      const u16* U = (const u16*)Bt;
#pragma unroll
      for (int j = 0; j < 4; ++j) {
        int c = (wid << 2) + j;
        gld_lds16(U + (size_t)(n0 + (c << 3) + srow) * ldb + k0 + skk,
                  (void*)&Bs[buf][c << 9]);
      }
    }
  };

  int cur = 0;
  stage(0, kb);
  for (int kt = 0; kt < nkt; ++kt) {
    __syncthreads();
    if (kt + 1 < nkt) stage(cur ^ 1, kb + (kt + 1) * GBK);
#pragma unroll
    for (int ks = 0; ks < 2; ++ks) {
      short8 a[4], b[4];
      const int ko = (ks << 5) + ((lane >> 4) << 3);
#pragma unroll
      for (int mi = 0; mi < 4; ++mi)
        a[mi] = *(const short8*)&As[cur][((wr << 6) + (mi << 4) + (lane & 15)) * GBK + ko];
#pragma unroll
      for (int ni = 0; ni < 4; ++ni)
        b[ni] = *(const short8*)&Bs[cur][((wc << 6) + (ni << 4) + (lane & 15)) * GBK + ko];
#pragma unroll
      for (int mi = 0; mi < 4; ++mi)
#pragma unroll
        for (int ni = 0; ni < 4; ++ni)
          acc[mi][ni] = __builtin_amdgcn_mfma_f32_16x16x32_bf16(a[mi], b[ni], acc[mi][ni], 0, 0, 0);
    }
    cur ^= 1;
  }

  if (fused) {
    u16* ts = (u16*)&As[0][0];
    if (outT) __syncthreads();
#pragma unroll
    for (int mi = 0; mi < 4; ++mi) {
#pragma unroll
      for (int ni = 0; ni < 4; ++ni) {
        const int ml0 = (wr << 6) + (mi << 4) + ((lane >> 4) << 2);
        const int nl = (wc << 6) + (ni << 4) + (lane & 15);
        const int n = n0 + nl;
        const float bv = bias ? bias[n] : 0.f;
#pragma unroll
        for (int r = 0; r < 4; ++r) {
          const int ml = ml0 + r;
          const size_t idx = (size_t)(m0 + ml) * DIMN + n;
          float t = acc[mi][ni][r] + bv;
          if (addmat) t += bf2f(addmat[idx]);
          if (do_relu) t = fmaxf(t, 0.f);
          if (resid) t += resid[idx];
          if (outf) outf[idx] = t;
          const u16 q = f2bf(t);
          if (out16) out16[idx] = q;
          if (outT) ts[ml * 128 + (nl ^ ((ml & 7) << 3))] = q;
        }
      }
    }
    if (outT) {
      __syncthreads();
      const int nl = tid >> 1;
      const int mh = (tid & 1) << 6;
#pragma unroll
      for (int c8 = 0; c8 < 8; ++c8) {
        const int mB = mh + (c8 << 3);
        short8 v;
#pragma unroll
        for (int e = 0; e < 8; ++e)
          v[e] = (short)ts[(mB + e) * 128 + (nl ^ (((mB + e) & 7) << 3))];
        *(short8*)&outT[(size_t)(n0 + nl) * M + (m0 + mB)] = v;
      }
    }
  } else {
    u16* Pz = P + (size_t)bz * (size_t)M * DIMN;
#pragma unroll
    for (int mi = 0; mi < 4; ++mi) {
#pragma unroll
      for (int ni = 0; ni < 4; ++ni) {
        const int mb = m0 + (wr << 6) + (mi << 4) + ((lane >> 4) << 2);
        const int n = n0 + (wc << 6) + (ni << 4) + (lane & 15);
#pragma unroll
        for (int r = 0; r < 4; ++r)
          Pz[(size_t)(mb + r) * DIMN + n] = f2bf(acc[mi][ni][r]);
      }
    }
  }
}

// ---- finalize: t = sum_s P[s](bf16)*scale -> out (f32) and/or out16 (bf16) --------
__global__ __launch_bounds__(256)
void finalize_k(const u16* __restrict__ P, int S, int Mrows, float scale,
                float* __restrict__ out, u16* __restrict__ out16)
{
  const size_t MN = (size_t)Mrows * DIMN;
  const size_t i4 = (((size_t)blockIdx.x * blockDim.x) + threadIdx.x) * 4;
  if (i4 >= MN) return;
  floatx4 v = {0.f, 0.f, 0.f, 0.f};
  for (int s = 0; s < S; ++s) {
    ushort4v p4 = *(const ushort4v*)(P + (size_t)s * MN + i4);
#pragma unroll
    for (int j = 0; j < 4; ++j) v[j] += bf2f(p4[j]);
  }
  floatx4 o;
#pragma unroll
  for (int j = 0; j < 4; ++j) o[j] = v[j] * scale;
  if (out) *(floatx4*)(out + i4) = o;
  if (out16) {
    unsigned long long q = 0;
#pragma unroll
    for (int j = 0; j < 4; ++j) q |= ((unsigned long long)f2bf(o[j])) << (16 * j);
    *(unsigned long long*)(out16 + i4) = q;
  }
}

// ---- fused finalize + transpose: sum S bf16 slabs *scale -> outf[M][256] f32
// ---- and outT[256][M] bf16. 64x64 tiles. ------------------------------------------
__global__ __launch_bounds__(256)
void finalize_tr_k(const u16* __restrict__ P, int S, int Mrows, float scale,
                   float* __restrict__ outf, u16* __restrict__ outT, int ldT)
{
  __shared__ __align__(16) u16 t[64][64];
  const size_t MN = (size_t)Mrows * DIMN;
  const int r0 = blockIdx.x << 6;
  const int c0 = blockIdx.y << 6;
  const int tid = threadIdx.x;
  const int lr = tid >> 3;
  const int lc = (tid & 7) << 3;
#pragma unroll
  for (int h = 0; h < 2; ++h) {
    const int r = lr + (h << 5);
    const size_t gi = (size_t)(r0 + r) * DIMN + (c0 + lc);
    float a[8];
#pragma unroll
    for (int e = 0; e < 8; ++e) a[e] = 0.f;
    for (int s = 0; s < S; ++s) {
      short8 p = *(const short8*)(P + (size_t)s * MN + gi);
#pragma unroll
      for (int e = 0; e < 8; ++e) a[e] += bf2f((u16)p[e]);
    }
    short8 v;
    floatx4 o0, o1;
#pragma unroll
    for (int e = 0; e < 4; ++e) {
      o0[e] = a[e] * scale; o1[e] = a[4 + e] * scale;
      v[e] = (short)f2bf(o0[e]); v[4 + e] = (short)f2bf(o1[e]);
    }
    *(floatx4*)(outf + gi) = o0;
    *(floatx4*)(outf + gi + 4) = o1;
    *(short8*)&t[r][lc ^ ((r >> 3) << 3)] = v;
  }
  __syncthreads();
#pragma unroll
  for (int h = 0; h < 2; ++h) {
    const int oc = lr + (h << 5);
    short8 v;
#pragma unroll
    for (int e = 0; e < 8; ++e)
      v[e] = (short)t[lc + e][oc ^ ((lc >> 3) << 3)];
    *(short8*)&outT[(size_t)(c0 + oc) * ldT + (r0 + lc)] = v;
  }
}

// -------- transpose (f32 or bf16 in, bf16 out); optional straight bf16 copy --------
__global__ __launch_bounds__(256)
void transpose_k(const void* __restrict__ in, int is32, int ldin,
                 u16* __restrict__ out, int ldout, u16* __restrict__ copy16)
{
  __shared__ __align__(16) u16 t[64][64];
  const int c0 = blockIdx.x << 6;
  const int r0 = blockIdx.y << 6;
  const int tid = threadIdx.x;
  const int lr = tid >> 3;
  const int lc = (tid & 7) << 3;
#pragma unroll
  for (int h = 0; h < 2; ++h) {
    const int r = lr + (h << 5);
    short8 v;
    if (is32) {
      const float* F = (const float*)in;
      const size_t gi = (size_t)(r0 + r) * ldin + (c0 + lc);
      floatx4 f0 = *(const floatx4*)(F + gi);
      floatx4 f1 = *(const floatx4*)(F + gi + 4);
#pragma unroll
      for (int e = 0; e < 4; ++e) { v[e] = (short)f2bf(f0[e]); v[4 + e] = (short)f2bf(f1[e]); }
      if (copy16) *(short8*)(copy16 + gi) = v;
    } else {
      v = *(const short8*)((const u16*)in + (size_t)(r0 + r) * ldin + (c0 + lc));
    }
    *(short8*)&t[r][lc ^ ((r >> 3) << 3)] = v;
  }
  __syncthreads();
#pragma unroll
  for (int h = 0; h < 2; ++h) {
    const int oc = lr + (h << 5);
    short8 v;
#pragma unroll
    for (int e = 0; e < 8; ++e)
      v[e] = (short)t[lc + e][oc ^ ((lc >> 3) << 3)];
    *(short8*)&out[(size_t)(c0 + oc) * ldout + (r0 + lc)] = v;
  }
}

// -------- elementwise f32 -> bf16 convert (8 elems/thread, grid-stride) -------------
__global__ __launch_bounds__(256)
void cvt8_k(const float* __restrict__ in, u16* __restrict__ out, size_t n)
{
  const size_t stride = (size_t)gridDim.x * 2048;
  for (size_t i = (((size_t)blockIdx.x << 8) + threadIdx.x) << 3; i < n; i += stride) {
    floatx4 f0 = *(const floatx4*)(in + i);
    floatx4 f1 = *(const floatx4*)(in + i + 4);
    short8 v;
#pragma unroll
    for (int e = 0; e < 4; ++e) { v[e] = (short)f2bf(f0[e]); v[4 + e] = (short)f2bf(f1[e]); }
    *(short8*)(out + i) = v;
  }
}

// -------- f = mean_t |x_p[faces[f,t]] - x_d[f]|  (f32 in, bf16 out) ----------------
__global__ __launch_bounds__(256)
void face_gather_k(const float* __restrict__ xp, const float* __restrict__ xd,
                   const int* __restrict__ faces, u16* __restrict__ f)
{
  const int fi = blockIdx.x;
  const int j = threadIdx.x;
  const int a = faces[fi * 3 + 0];
  const int b = faces[fi * 3 + 1];
  const int c = faces[fi * 3 + 2];
  const float xv = xd[(size_t)fi * DIMN + j];
  const float s = fabsf(xp[(size_t)a * DIMN + j] - xv)
                + fabsf(xp[(size_t)b * DIMN + j] - xv)
                + fabsf(xp[(size_t)c * DIMN + j] - xv);
  f[(size_t)fi * DIMN + j] = f2bf(s * (1.0f / 3.0f));
}

extern "C" void kernel_launch(void* const* d_in, const int* in_sizes, int n_in,
                              void* d_out, int out_size, void* d_ws, size_t ws_size,
                              hipStream_t stream)
{
  (void)in_sizes; (void)n_in; (void)out_size;
  const float* primal   = (const float*)d_in[0];
  const float* A_primal = (const float*)d_in[1];
  const float* A_dual   = (const float*)d_in[2];
  const float* A        = (const float*)d_in[3];
  const int* faces      = (const int*)d_in[4];
  const float* pW  = (const float*)d_in[5];
  const float* pb  = (const float*)d_in[6];
  const float* pgW = (const float*)d_in[7];
  const float* pgb = (const float*)d_in[8];
  const float* dW  = (const float*)d_in[9];
  const float* db  = (const float*)d_in[10];
  const float* dgW = (const float*)d_in[11];
  const float* dgb = (const float*)d_in[12];
  const float* Wp  = (const float*)d_in[13];
  const float* bp  = (const float*)d_in[14];
  const float* Wd  = (const float*)d_in[15];
  const float* bd  = (const float*)d_in[16];

  char* wsp = (char*)d_ws;
  auto alloc = [&](size_t bytes) -> void* {
    void* p = (void*)wsp;
    wsp += (bytes + 255) & ~(size_t)255;
    return p;
  };
  const size_t NVD = (size_t)kNV * DIMN, NFD = (size_t)kNF * DIMN;
  u16* XTp   = (u16*)alloc(NVD * 2);                 // x_p^T [256][6144]
  u16* XTd   = (u16*)alloc(NFD * 2);                 // x_d^T [256][12288]
  u16* TB    = (u16*)alloc(NFD * 2);                 // fc^T / f^T [256][M]
  u16* t1    = (u16*)alloc(NFD * 2);                 // Adj@X sum / face f (bf16)
  u16* fc    = (u16*)alloc(NFD * 2);                 // out_fc / mapped (bf16)
  float* xp3 = (float*)alloc(NVD * 4);               // final x_p (race-safe)
  float* xd3 = (float*)alloc(NFD * 4);               // final x_d (race-safe)
  u16* P     = (u16*)alloc((size_t)8 * NFD * 2);     // bf16 split-K partials 50MB
  const size_t bigElems = (size_t)kNF * kNF + 2 * (size_t)kNF * kNV + (size_t)kNV * kNV;
  const size_t need = (size_t)(wsp - (char*)d_ws) + bigElems * 2 + 4096;
  const bool big = ws_size >= need;
  u16 *Ad16 = nullptr, *At16 = nullptr, *A16 = nullptr, *Ap16 = nullptr;
  if (big) {
    Ad16 = (u16*)alloc((size_t)kNF * kNF * 2);
    At16 = (u16*)alloc((size_t)kNF * kNV * 2);
    A16  = (u16*)alloc((size_t)kNV * kNF * 2);
    Ap16 = (u16*)alloc((size_t)kNV * kNV * 2);
  }

  float* out0  = (float*)d_out;      // out_primal + x_p
  float* out1  = out0 + NVD;         // out_dual + x_d
  float* pouts = out1 + NFD;         // primal_outs x3 (f32)
  float* douts = pouts + 3 * NVD;    // dual_outs x3 (f32)

  // pipelined partial GEMM (bf16 A, bf16 B) — big adjacency shapes
  auto gemm8 = [&](const u16* Ap, int lda, const u16* Btp, int ldb,
                   int M, int K, int S) {
    const int nx = M / 128;
    gemm8_k<<<dim3(nx * S), dim3(512), 0, stream>>>(Ap, lda, Btp, ldb, P, M, nx, K / S);
  };
  // legacy split-K partial GEMM (fallback path)
  auto gemmP = [&](const void* A0p, int a0mode, int lda0,
                   const u16* Btp, int ldb, int M, int K, int S) {
    const int nx = M / 128;
    gemm_bf16_k<<<dim3(nx * 2 * S), dim3(256), 0, stream>>>(
        A0p, a0mode, lda0, nullptr, 0, 0, K, Btp, 0, ldb,
        P, M, nx, K / S, 0, nullptr, nullptr, 0, nullptr, nullptr, nullptr, nullptr);
  };
  // fused GEMM with epilogue; optional A1 concat segment; optional outT
  auto gemmF = [&](const void* A0p, int a0mode, int lda0,
                   const void* A1p, int a1mode, int lda1, int K1,
                   const void* Btp, int btis32, int ldb, int M, int K,
                   const float* bias, const u16* add, int relu,
                   const float* resid, float* outf, u16* out16, u16* outT) {
    const int nx = M / 128;
    gemm_bf16_k<<<dim3(nx * 2), dim3(256), 0, stream>>>(
        A0p, a0mode, lda0, A1p, a1mode, lda1, K1, Btp, btis32, ldb,
        P, M, nx, K, 1, bias, add, relu, resid, outf, out16, outT);
  };
  auto fin = [&](int M, int S, float scale, float* out, u16* out16) {
    finalize_k<<<dim3((unsigned)((size_t)M * DIMN / 1024)), dim3(256), 0, stream>>>(
        P, S, M, scale, out, out16);
  };
  auto tranp = [&](const void* in, int is32, int ldin, u16* out, int ldout,
                   int R, int C, u16* copy16) {
    transpose_k<<<dim3(C / 64, R / 64), dim3(256), 0, stream>>>(
        in, is32, ldin, out, ldout, copy16);
  };
  auto cvt = [&](const float* in, u16* out, size_t n) {
    cvt8_k<<<dim3(2048), dim3(256), 0, stream>>>(in, out, n);
  };

  // ---- one-time prep ----
  if (big) {
    cvt(A_dual, Ad16, (size_t)kNF * kNF);
    cvt(A_primal, Ap16, (size_t)kNV * kNV);
    tranp(A, 1, kNF, At16, kNV, kNV, kNF, A16);      // At16 + A16 in one pass
  }
  tranp(primal, 1, DIMN, XTp, kNV, kNV, DIMN, nullptr);
  hipMemcpyAsync(pouts, primal, NVD * 4, hipMemcpyDeviceToDevice, stream);

  // ---- x_d = (1/3) A^T @ primal -> douts[0] (f32) + XTd (bf16 transposed) ----
  if (big) {
    gemm8(At16, kNV, XTp, kNV, kNF, kNV, 8);                        // grid 768
    finalize_tr_k<<<dim3(kNF / 64, 4), dim3(256), 0, stream>>>(
        P, 8, kNF, 1.0f / 3.0f, douts, XTd, kNF);
  } else {
    for (int s = 0; s < kNF / SLAB; ++s) {
      const int m0 = s * SLAB;
      tranp(A + m0, 1, kNF, TB, kNV, kNV, SLAB, nullptr);
      gemmP(TB, 0, kNV, XTp, kNV, SLAB, kNV, 16);
      finalize_k<<<dim3((unsigned)((size_t)SLAB * DIMN / 1024)), dim3(256), 0, stream>>>(
          P, 16, SLAB, 1.0f / 3.0f, douts + (size_t)m0 * DIMN, nullptr);
    }
    tranp(douts, 1, DIMN, XTd, kNF, kNF, DIMN, nullptr);
  }

  // ---- primal AGG layers (x_p f32 in pouts slots; x_p^T maintained in XTp) ----
  const float* xpc = primal;
  for (int i = 0; i < 3; ++i) {
    if (big) gemm8(Ap16, kNV, XTp, kNV, kNV, kNV, 16);              // Ap@X -> P(16)
    else     gemmP(A_primal, 1, kNV, XTp, kNV, kNV, kNV, 8);
    fin(kNV, big ? 16 : 8, 1.f, nullptr, t1);
    gemmF(t1, 0, 256, nullptr, 0, 0, 256,
          pW + (size_t)i * 65536, 1, 256, kNV, 256,
          pb + i * 256, nullptr, 0, nullptr, nullptr, fc, TB);      // fc + fc^T
    if (big) gemm8(Ap16, kNV, TB, kNV, kNV, kNV, 16);               // Ap@fc -> P(16)
    else     gemmP(A_primal, 1, kNV, TB, kNV, kNV, kNV, 8);
    fin(kNV, big ? 16 : 8, 1.f, nullptr, t1);
    float* nxt = (i < 2) ? (pouts + (size_t)(i + 1) * NVD) : xp3;
    u16* xtT = (i < 2) ? XTp : nullptr;
    gemmF(t1, 0, 256, nullptr, 0, 0, 256,
          pgW + (size_t)i * 65536, 1, 256, kNV, 256,
          pgb + i * 256, fc, 1, xpc, nxt, nullptr, xtT);            // relu(fc+og)+x
    xpc = nxt;
  }

  // ---- dual AGG layers (x_d f32 in douts slots; x_d^T maintained in XTd) ----
  const float* xdc = douts;
  for (int i = 0; i < 3; ++i) {
    if (big) gemm8(Ad16, kNF, XTd, kNF, kNF, kNF, 8);               // Ad@X -> P(8)
    else     gemmP(A_dual, 1, kNF, XTd, kNF, kNF, kNF, 4);
    fin(kNF, big ? 8 : 4, 1.f, nullptr, t1);
    gemmF(t1, 0, 256, nullptr, 0, 0, 256,
          dW + (size_t)i * 65536, 1, 256, kNF, 256,
          db + i * 256, nullptr, 0, nullptr, nullptr, fc, TB);
    if (big) gemm8(Ad16, kNF, TB, kNF, kNF, kNF, 8);                // Ad@fc -> P(8)
    else     gemmP(A_dual, 1, kNF, TB, kNF, kNF, kNF, 4);
    fin(kNF, big ? 8 : 4, 1.f, nullptr, t1);
    float* nxt = (i < 2) ? (douts + (size_t)(i + 1) * NFD) : xd3;
    u16* xtT = (i < 2) ? XTd : nullptr;
    gemmF(t1, 0, 256, nullptr, 0, 0, 256,
          dgW + (size_t)i * 65536, 1, 256, kNF, 256,
          dgb + i * 256, fc, 1, xdc, nxt, nullptr, xtT);
    xdc = nxt;
  }

  // ---- PDF ----
  face_gather_k<<<dim3(kNF), dim3(256), 0, stream>>>(xp3, xd3, faces, t1);  // f bf16
  tranp(t1, 0, DIMN, TB, kNF, kNF, DIMN, nullptr);                          // f^T
  // out_dual = relu([x_d, f] @ Wd^T + bd) + x_d
  gemmF(xd3, 1, 256, t1, 0, 256, 256, Wd, 1, 512, kNF, 512,
        bd, nullptr, 1, xd3, out1, nullptr, nullptr);
  // mapped = A @ f -> P -> fc (bf16)
  if (big) { gemm8(A16, kNF, TB, kNF, kNV, kNF, 16); fin(kNV, 16, 1.f, nullptr, fc); }
  else     { gemmP(A, 1, kNF, TB, kNF, kNV, kNF, 8); fin(kNV, 8, 1.f, nullptr, fc); }
  // out_primal = relu([x_p, mapped] @ Wp^T + bp) + x_p
  gemmF(xp3, 1, 256, fc, 0, 256, 256, Wp, 1, 512, kNV, 512,
        bp, nullptr, 1, xp3, out0, nullptr, nullptr);
}

// Round 13
// 1798.893 us; speedup vs baseline: 1.2107x; 1.2107x over previous
//
#include <hip/hip_runtime.h>

// TwoStreamNet on MI355X — f32 I/O, bf16 MFMA internals.
// R13: two-job merged launches (primal+dual streams share one dispatch) —
//      44 -> 30 kernel launches; inner GEMM/fin code identical to R11 (proven).

typedef short short8 __attribute__((ext_vector_type(8)));
typedef float floatx4 __attribute__((ext_vector_type(4)));
typedef unsigned short ushort4v __attribute__((ext_vector_type(4)));
typedef unsigned short u16;

#define DIMN 256
#define GBK 64

static const int kNV = 6144;
static const int kNF = 12288;
static const int SLAB = 768;

__device__ __forceinline__ float bf2f(u16 u) {
  union { unsigned int i; float f; } x; x.i = ((unsigned int)u) << 16; return x.f;
}
__device__ __forceinline__ u16 f2bf(float f) {
  union { float f; unsigned int i; } x; x.f = f;
  unsigned int r = x.i + 0x7fffu + ((x.i >> 16) & 1u);
  return (u16)(r >> 16);
}
__device__ __forceinline__ void gld_lds16(const void* g, void* l) {
  __builtin_amdgcn_global_load_lds((__attribute__((address_space(1))) void*)(g),
                                   (__attribute__((address_space(3))) void*)(l),
                                   16, 0, 0);
}

// ---- job descriptors ---------------------------------------------------------------
struct GJ {   // GEMM job: C = A(M x K) * Bt(256 x K)^T, m97 structure
  const void* A0; int A0mode; int lda0;            // mode: 0 bf16 gld_lds, 1 f32 cvt
  const void* A1; int A1mode; int lda1; int K1;    // optional concat segment
  const void* Bt; int Btis32; int ldb;
  u16* P; int M; int nx; int kchunk;               // fused=0: bf16 partials -> P[bz]
  int fused;                                       // fused=1: epilogue below
  const float* bias; const u16* addmat; int do_relu;
  const float* resid; float* outf; u16* out16; u16* outT;
};
struct FJ {   // finalize job: out = sum_s P[s] * scale
  const u16* P; int S; int Mrows; float scale; float* out; u16* out16;
};

// ---- GEMM device body (identical math to R11's gemm_bf16_k) ------------------------
__device__ __forceinline__ void gemm_dev(const GJ& j, int bid)
{
  __shared__ __align__(16) u16 As[2][128 * GBK];
  __shared__ __align__(16) u16 Bs[2][128 * GBK];

  const int y = bid & 1;
  const int bx = (bid >> 1) % j.nx;
  const int bz = (bid >> 1) / j.nx;
  const int m0 = bx << 7;
  const int n0 = y << 7;
  const int kb = bz * j.kchunk;
  const int nkt = j.kchunk / GBK;

  const int tid = threadIdx.x;
  const int wid = tid >> 6;
  const int lane = tid & 63;
  const int wr = wid >> 1, wc = wid & 1;
  const int srow = lane >> 3;
  const int skk = (lane & 7) << 3;

  floatx4 acc[4][4];
  floatx4 zz = {0.f, 0.f, 0.f, 0.f};
#pragma unroll
  for (int i = 0; i < 4; ++i)
#pragma unroll
    for (int jj = 0; jj < 4; ++jj) acc[i][jj] = zz;

  auto stage = [&](int buf, int k0) {
    const void* base; int lda, mode, kl;
    if (k0 < j.K1) { base = j.A0; lda = j.lda0; mode = j.A0mode; kl = k0; }
    else           { base = j.A1; lda = j.lda1; mode = j.A1mode; kl = k0 - j.K1; }
    if (mode == 0) {
      const u16* U = (const u16*)base;
#pragma unroll
      for (int q = 0; q < 4; ++q) {
        int c = (wid << 2) + q;
        gld_lds16(U + (size_t)(m0 + (c << 3) + srow) * lda + kl + skk,
                  (void*)&As[buf][c << 9]);
      }
    } else {
      const float* F = (const float*)base;
#pragma unroll
      for (int q = 0; q < 4; ++q) {
        int c = (wid << 2) + q;
        const size_t gi = (size_t)(m0 + (c << 3) + srow) * lda + kl + skk;
        floatx4 f0 = *(const floatx4*)(F + gi);
        floatx4 f1 = *(const floatx4*)(F + gi + 4);
        short8 v;
#pragma unroll
        for (int e = 0; e < 4; ++e) { v[e] = (short)f2bf(f0[e]); v[4 + e] = (short)f2bf(f1[e]); }
        *(short8*)&As[buf][(c << 9) + (lane << 3)] = v;
      }
    }
    if (j.Btis32) {
      const float* F = (const float*)j.Bt;
#pragma unroll
      for (int q = 0; q < 4; ++q) {
        int c = (wid << 2) + q;
        const size_t gi = (size_t)(n0 + (c << 3) + srow) * j.ldb + k0 + skk;
        floatx4 f0 = *(const floatx4*)(F + gi);
        floatx4 f1 = *(const floatx4*)(F + gi + 4);
        short8 v;
#pragma unroll
        for (int e = 0; e < 4; ++e) { v[e] = (short)f2bf(f0[e]); v[4 + e] = (short)f2bf(f1[e]); }
        *(short8*)&Bs[buf][(c << 9) + (lane << 3)] = v;
      }
    } else {
      const u16* U = (const u16*)j.Bt;
#pragma unroll
      for (int q = 0; q < 4; ++q) {
        int c = (wid << 2) + q;
        gld_lds16(U + (size_t)(n0 + (c << 3) + srow) * j.ldb + k0 + skk,
                  (void*)&Bs[buf][c << 9]);
      }
    }
  };

  int cur = 0;
  stage(0, kb);
  for (int kt = 0; kt < nkt; ++kt) {
    __syncthreads();
    if (kt + 1 < nkt) stage(cur ^ 1, kb + (kt + 1) * GBK);
#pragma unroll
    for (int ks = 0; ks < 2; ++ks) {
      short8 a[4], b[4];
      const int ko = (ks << 5) + ((lane >> 4) << 3);
#pragma unroll
      for (int mi = 0; mi < 4; ++mi)
        a[mi] = *(const short8*)&As[cur][((wr << 6) + (mi << 4) + (lane & 15)) * GBK + ko];
#pragma unroll
      for (int ni = 0; ni < 4; ++ni)
        b[ni] = *(const short8*)&Bs[cur][((wc << 6) + (ni << 4) + (lane & 15)) * GBK + ko];
#pragma unroll
      for (int mi = 0; mi < 4; ++mi)
#pragma unroll
        for (int ni = 0; ni < 4; ++ni)
          acc[mi][ni] = __builtin_amdgcn_mfma_f32_16x16x32_bf16(a[mi], b[ni], acc[mi][ni], 0, 0, 0);
    }
    cur ^= 1;
  }

  if (j.fused) {
    u16* ts = (u16*)&As[0][0];
    if (j.outT) __syncthreads();
#pragma unroll
    for (int mi = 0; mi < 4; ++mi) {
#pragma unroll
      for (int ni = 0; ni < 4; ++ni) {
        const int ml0 = (wr << 6) + (mi << 4) + ((lane >> 4) << 2);
        const int nl = (wc << 6) + (ni << 4) + (lane & 15);
        const int n = n0 + nl;
        const float bv = j.bias ? j.bias[n] : 0.f;
#pragma unroll
        for (int r = 0; r < 4; ++r) {
          const int ml = ml0 + r;
          const size_t idx = (size_t)(m0 + ml) * DIMN + n;
          float t = acc[mi][ni][r] + bv;
          if (j.addmat) t += bf2f(j.addmat[idx]);
          if (j.do_relu) t = fmaxf(t, 0.f);
          if (j.resid) t += j.resid[idx];
          if (j.outf) j.outf[idx] = t;
          const u16 q = f2bf(t);
          if (j.out16) j.out16[idx] = q;
          if (j.outT) ts[ml * 128 + (nl ^ ((ml & 7) << 3))] = q;
        }
      }
    }
    if (j.outT) {
      __syncthreads();
      const int nl = tid >> 1;
      const int mh = (tid & 1) << 6;
#pragma unroll
      for (int c8 = 0; c8 < 8; ++c8) {
        const int mB = mh + (c8 << 3);
        short8 v;
#pragma unroll
        for (int e = 0; e < 8; ++e)
          v[e] = (short)ts[(mB + e) * 128 + (nl ^ (((mB + e) & 7) << 3))];
        *(short8*)&j.outT[(size_t)(n0 + nl) * j.M + (m0 + mB)] = v;
      }
    }
  } else {
    u16* Pz = j.P + (size_t)bz * (size_t)j.M * DIMN;
#pragma unroll
    for (int mi = 0; mi < 4; ++mi) {
#pragma unroll
      for (int ni = 0; ni < 4; ++ni) {
        const int mb = m0 + (wr << 6) + (mi << 4) + ((lane >> 4) << 2);
        const int n = n0 + (wc << 6) + (ni << 4) + (lane & 15);
#pragma unroll
        for (int r = 0; r < 4; ++r)
          Pz[(size_t)(mb + r) * DIMN + n] = f2bf(acc[mi][ni][r]);
      }
    }
  }
}

__global__ __launch_bounds__(256, 2) void gemm1_k(GJ j0) { gemm_dev(j0, blockIdx.x); }
__global__ __launch_bounds__(256, 2) void gemm2_k(GJ j0, GJ j1, int nb0) {
  if ((int)blockIdx.x < nb0) gemm_dev(j0, blockIdx.x);
  else                       gemm_dev(j1, blockIdx.x - nb0);
}

// ---- finalize ----------------------------------------------------------------------
__device__ __forceinline__ void fin_dev(const FJ& f, int bid)
{
  const size_t MN = (size_t)f.Mrows * DIMN;
  const size_t i4 = (((size_t)bid << 8) + threadIdx.x) * 4;
  if (i4 >= MN) return;
  floatx4 v = {0.f, 0.f, 0.f, 0.f};
  for (int s = 0; s < f.S; ++s) {
    ushort4v p4 = *(const ushort4v*)(f.P + (size_t)s * MN + i4);
#pragma unroll
    for (int q = 0; q < 4; ++q) v[q] += bf2f(p4[q]);
  }
  floatx4 o;
#pragma unroll
  for (int q = 0; q < 4; ++q) o[q] = v[q] * f.scale;
  if (f.out) *(floatx4*)(f.out + i4) = o;
  if (f.out16) {
    unsigned long long qq = 0;
#pragma unroll
    for (int q = 0; q < 4; ++q) qq |= ((unsigned long long)f2bf(o[q])) << (16 * q);
    *(unsigned long long*)(f.out16 + i4) = qq;
  }
}
__global__ __launch_bounds__(256) void fin1_k(FJ f0) { fin_dev(f0, blockIdx.x); }
__global__ __launch_bounds__(256) void fin2_k(FJ f0, FJ f1, int nb0) {
  if ((int)blockIdx.x < nb0) fin_dev(f0, blockIdx.x);
  else                       fin_dev(f1, blockIdx.x - nb0);
}

// ---- fused finalize + transpose (x_d): sum S slabs *scale -> outf + outT ----------
__global__ __launch_bounds__(256)
void finalize_tr_k(const u16* __restrict__ P, int S, int Mrows, float scale,
                   float* __restrict__ outf, u16* __restrict__ outT, int ldT)
{
  __shared__ __align__(16) u16 t[64][64];
  const size_t MN = (size_t)Mrows * DIMN;
  const int r0 = blockIdx.x << 6;
  const int c0 = blockIdx.y << 6;
  const int tid = threadIdx.x;
  const int lr = tid >> 3;
  const int lc = (tid & 7) << 3;
#pragma unroll
  for (int h = 0; h < 2; ++h) {
    const int r = lr + (h << 5);
    const size_t gi = (size_t)(r0 + r) * DIMN + (c0 + lc);
    float a[8];
#pragma unroll
    for (int e = 0; e < 8; ++e) a[e] = 0.f;
    for (int s = 0; s < S; ++s) {
      short8 p = *(const short8*)(P + (size_t)s * MN + gi);
#pragma unroll
      for (int e = 0; e < 8; ++e) a[e] += bf2f((u16)p[e]);
    }
    short8 v;
    floatx4 o0, o1;
#pragma unroll
    for (int e = 0; e < 4; ++e) {
      o0[e] = a[e] * scale; o1[e] = a[4 + e] * scale;
      v[e] = (short)f2bf(o0[e]); v[4 + e] = (short)f2bf(o1[e]);
    }
    *(floatx4*)(outf + gi) = o0;
    *(floatx4*)(outf + gi + 4) = o1;
    *(short8*)&t[r][lc ^ ((r >> 3) << 3)] = v;
  }
  __syncthreads();
#pragma unroll
  for (int h = 0; h < 2; ++h) {
    const int oc = lr + (h << 5);
    short8 v;
#pragma unroll
    for (int e = 0; e < 8; ++e)
      v[e] = (short)t[lc + e][oc ^ ((lc >> 3) << 3)];
    *(short8*)&outT[(size_t)(c0 + oc) * ldT + (r0 + lc)] = v;
  }
}

// ---- transpose (f32 or bf16 in, bf16 out); optional straight bf16 copy ------------
__global__ __launch_bounds__(256)
void transpose_k(const void* __restrict__ in, int is32, int ldin,
                 u16* __restrict__ out, int ldout, u16* __restrict__ copy16)
{
  __shared__ __align__(16) u16 t[64][64];
  const int c0 = blockIdx.x << 6;
  const int r0 = blockIdx.y << 6;
  const int tid = threadIdx.x;
  const int lr = tid >> 3;
  const int lc = (tid & 7) << 3;
#pragma unroll
  for (int h = 0; h < 2; ++h) {
    const int r = lr + (h << 5);
    short8 v;
    if (is32) {
      const float* F = (const float*)in;
      const size_t gi = (size_t)(r0 + r) * ldin + (c0 + lc);
      floatx4 f0 = *(const floatx4*)(F + gi);
      floatx4 f1 = *(const floatx4*)(F + gi + 4);
#pragma unroll
      for (int e = 0; e < 4; ++e) { v[e] = (short)f2bf(f0[e]); v[4 + e] = (short)f2bf(f1[e]); }
      if (copy16) *(short8*)(copy16 + gi) = v;
    } else {
      v = *(const short8*)((const u16*)in + (size_t)(r0 + r) * ldin + (c0 + lc));
    }
    *(short8*)&t[r][lc ^ ((r >> 3) << 3)] = v;
  }
  __syncthreads();
#pragma unroll
  for (int h = 0; h < 2; ++h) {
    const int oc = lr + (h << 5);
    short8 v;
#pragma unroll
    for (int e = 0; e < 8; ++e)
      v[e] = (short)t[lc + e][oc ^ ((lc >> 3) << 3)];
    *(short8*)&out[(size_t)(c0 + oc) * ldout + (r0 + lc)] = v;
  }
}

// ---- elementwise f32 -> bf16 convert (8 elems/thread, grid-stride) ----------------
__global__ __launch_bounds__(256)
void cvt8_k(const float* __restrict__ in, u16* __restrict__ out, size_t n)
{
  const size_t stride = (size_t)gridDim.x * 2048;
  for (size_t i = (((size_t)blockIdx.x << 8) + threadIdx.x) << 3; i < n; i += stride) {
    floatx4 f0 = *(const floatx4*)(in + i);
    floatx4 f1 = *(const floatx4*)(in + i + 4);
    short8 v;
#pragma unroll
    for (int e = 0; e < 4; ++e) { v[e] = (short)f2bf(f0[e]); v[4 + e] = (short)f2bf(f1[e]); }
    *(short8*)(out + i) = v;
  }
}

// ---- f = mean_t |x_p[faces[f,t]] - x_d[f]|  (f32 in, bf16 out) --------------------
__global__ __launch_bounds__(256)
void face_gather_k(const float* __restrict__ xp, const float* __restrict__ xd,
                   const int* __restrict__ faces, u16* __restrict__ f)
{
  const int fi = blockIdx.x;
  const int jj = threadIdx.x;
  const int a = faces[fi * 3 + 0];
  const int b = faces[fi * 3 + 1];
  const int c = faces[fi * 3 + 2];
  const float xv = xd[(size_t)fi * DIMN + jj];
  const float s = fabsf(xp[(size_t)a * DIMN + jj] - xv)
                + fabsf(xp[(size_t)b * DIMN + jj] - xv)
                + fabsf(xp[(size_t)c * DIMN + jj] - xv);
  f[(size_t)fi * DIMN + jj] = f2bf(s * (1.0f / 3.0f));
}

extern "C" void kernel_launch(void* const* d_in, const int* in_sizes, int n_in,
                              void* d_out, int out_size, void* d_ws, size_t ws_size,
                              hipStream_t stream)
{
  (void)in_sizes; (void)n_in; (void)out_size;
  const float* primal   = (const float*)d_in[0];
  const float* A_primal = (const float*)d_in[1];
  const float* A_dual   = (const float*)d_in[2];
  const float* A        = (const float*)d_in[3];
  const int* faces      = (const int*)d_in[4];
  const float* pW  = (const float*)d_in[5];
  const float* pb  = (const float*)d_in[6];
  const float* pgW = (const float*)d_in[7];
  const float* pgb = (const float*)d_in[8];
  const float* dW  = (const float*)d_in[9];
  const float* db  = (const float*)d_in[10];
  const float* dgW = (const float*)d_in[11];
  const float* dgb = (const float*)d_in[12];
  const float* Wp  = (const float*)d_in[13];
  const float* bp  = (const float*)d_in[14];
  const float* Wd  = (const float*)d_in[15];
  const float* bd  = (const float*)d_in[16];

  char* wsp = (char*)d_ws;
  auto alloc = [&](size_t bytes) -> void* {
    void* p = (void*)wsp;
    wsp += (bytes + 255) & ~(size_t)255;
    return p;
  };
  const size_t NVD = (size_t)kNV * DIMN, NFD = (size_t)kNF * DIMN;
  u16* XTp   = (u16*)alloc(NVD * 2);                 // x_p^T [256][6144]
  u16* XTd   = (u16*)alloc(NFD * 2);                 // x_d^T [256][12288]
  u16* TBd   = (u16*)alloc(NFD * 2);                 // dual fc^T / f^T
  u16* TBp   = (u16*)alloc(NVD * 2);                 // primal fc^T
  u16* t1d   = (u16*)alloc(NFD * 2);                 // dual Adj@X sum / face f
  u16* t1p   = (u16*)alloc(NVD * 2);                 // primal Adj@X sum
  u16* fcd   = (u16*)alloc(NFD * 2);                 // dual out_fc
  u16* fcp   = (u16*)alloc(NVD * 2);                 // primal out_fc / mapped
  float* xp3 = (float*)alloc(NVD * 4);               // final x_p
  float* xd3 = (float*)alloc(NFD * 4);               // final x_d
  u16* P     = (u16*)alloc((size_t)8 * NFD * 2);     // partials: dual 4xNFD | primal 8xNVD
  u16* Pd    = P;
  u16* Pp    = P + 4 * NFD;
  const size_t bigElems = (size_t)kNF * kNF + 2 * (size_t)kNF * kNV + (size_t)kNV * kNV;
  const size_t need = (size_t)(wsp - (char*)d_ws) + bigElems * 2 + 4096;
  const bool big = ws_size >= need;
  u16 *Ad16 = nullptr, *At16 = nullptr, *A16 = nullptr, *Ap16 = nullptr;
  if (big) {
    Ad16 = (u16*)alloc((size_t)kNF * kNF * 2);
    At16 = (u16*)alloc((size_t)kNF * kNV * 2);
    A16  = (u16*)alloc((size_t)kNV * kNF * 2);
    Ap16 = (u16*)alloc((size_t)kNV * kNV * 2);
  }

  float* out0  = (float*)d_out;      // out_primal + x_p
  float* out1  = out0 + NVD;         // out_dual + x_d
  float* pouts = out1 + NFD;         // primal_outs x3 (f32)
  float* douts = pouts + 3 * NVD;    // dual_outs x3 (f32)

  auto GP = [&](const void* A0, int mode, int lda, const u16* Bt, int ldb,
                u16* Pr, int M, int K, int S) -> GJ {
    GJ g{}; g.A0 = A0; g.A0mode = mode; g.lda0 = lda;
    g.A1 = nullptr; g.A1mode = 0; g.lda1 = 0; g.K1 = K;
    g.Bt = Bt; g.Btis32 = 0; g.ldb = ldb;
    g.P = Pr; g.M = M; g.nx = M / 128; g.kchunk = K / S; g.fused = 0;
    g.bias = nullptr; g.addmat = nullptr; g.do_relu = 0; g.resid = nullptr;
    g.outf = nullptr; g.out16 = nullptr; g.outT = nullptr;
    return g;
  };
  auto GF = [&](const void* A0, int a0m, int lda0, const void* A1, int a1m,
                int lda1, int K1, const void* Bt, int bt32, int ldb, int M, int K,
                const float* bias, const u16* add, int relu, const float* resid,
                float* outf, u16* out16, u16* outT) -> GJ {
    GJ g{}; g.A0 = A0; g.A0mode = a0m; g.lda0 = lda0;
    g.A1 = A1; g.A1mode = a1m; g.lda1 = lda1; g.K1 = K1;
    g.Bt = Bt; g.Btis32 = bt32; g.ldb = ldb;
    g.P = P; g.M = M; g.nx = M / 128; g.kchunk = K; g.fused = 1;
    g.bias = bias; g.addmat = add; g.do_relu = relu; g.resid = resid;
    g.outf = outf; g.out16 = out16; g.outT = outT;
    return g;
  };
  auto gblk = [&](const GJ& g) { return g.nx * 2 * (g.fused ? 1 : (g.K1 / g.kchunk)); };
  auto launch2 = [&](const GJ& a, const GJ& b) {
    const int nb0 = gblk(a);
    gemm2_k<<<dim3(nb0 + gblk(b)), dim3(256), 0, stream>>>(a, b, nb0);
  };
  auto launch1 = [&](const GJ& a) {
    gemm1_k<<<dim3(gblk(a)), dim3(256), 0, stream>>>(a);
  };
  auto FIN = [&](const u16* Pr, int S, int M, float scale, float* out, u16* out16) -> FJ {
    FJ f{}; f.P = Pr; f.S = S; f.Mrows = M; f.scale = scale; f.out = out; f.out16 = out16;
    return f;
  };
  auto fblk = [&](const FJ& f) { return (int)((size_t)f.Mrows * DIMN / 1024); };
  auto fin2 = [&](const FJ& a, const FJ& b) {
    const int nb0 = fblk(a);
    fin2_k<<<dim3(nb0 + fblk(b)), dim3(256), 0, stream>>>(a, b, nb0);
  };
  auto fin1 = [&](const FJ& a) { fin1_k<<<dim3(fblk(a)), dim3(256), 0, stream>>>(a); };
  auto tranp = [&](const void* in, int is32, int ldin, u16* out, int ldout,
                   int R, int C, u16* copy16) {
    transpose_k<<<dim3(C / 64, R / 64), dim3(256), 0, stream>>>(
        in, is32, ldin, out, ldout, copy16);
  };
  auto cvt = [&](const float* in, u16* out, size_t n) {
    cvt8_k<<<dim3(2048), dim3(256), 0, stream>>>(in, out, n);
  };

  // ---- one-time prep ----
  if (big) {
    cvt(A_dual, Ad16, (size_t)kNF * kNF);
    cvt(A_primal, Ap16, (size_t)kNV * kNV);
    tranp(A, 1, kNF, At16, kNV, kNV, kNF, A16);      // At16 + A16 in one pass
  }
  tranp(primal, 1, DIMN, XTp, kNV, kNV, DIMN, nullptr);
  hipMemcpyAsync(pouts, primal, NVD * 4, hipMemcpyDeviceToDevice, stream);

  const void* ApP = big ? (const void*)Ap16 : (const void*)A_primal;
  const int apm = big ? 0 : 1;
  const void* AdP = big ? (const void*)Ad16 : (const void*)A_dual;
  const int adm = big ? 0 : 1;

  // ---- x_d = (1/3) A^T @ primal -> douts[0] (f32) + XTd ----
  if (big) {
    launch1(GP(At16, 0, kNV, XTp, kNV, Pd, kNF, kNV, 4));
    finalize_tr_k<<<dim3(kNF / 64, 4), dim3(256), 0, stream>>>(
        Pd, 4, kNF, 1.0f / 3.0f, douts, XTd, kNF);
  } else {
    for (int s = 0; s < kNF / SLAB; ++s) {
      const int m0 = s * SLAB;
      tranp(A + m0, 1, kNF, TBd, kNV, kNV, SLAB, nullptr);
      launch1(GP(TBd, 0, kNV, XTp, kNV, Pd, SLAB, kNV, 16));
      fin1(FIN(Pd, 16, SLAB, 1.0f / 3.0f, douts + (size_t)m0 * DIMN, nullptr));
    }
    tranp(douts, 1, DIMN, XTd, kNF, kNF, DIMN, nullptr);
  }

  // ---- AGG layers: primal+dual merged per step ----
  const float* xpc = primal;
  const float* xdc = douts;
  for (int i = 0; i < 3; ++i) {
    // G1: Ad@Xd (768 blk) + Ap@Xp (768 blk)
    launch2(GP(AdP, adm, kNF, XTd, kNF, Pd, kNF, kNF, 4),
            GP(ApP, apm, kNV, XTp, kNV, Pp, kNV, kNV, 8));
    // F1
    fin2(FIN(Pd, 4, kNF, 1.f, nullptr, t1d), FIN(Pp, 8, kNV, 1.f, nullptr, t1p));
    // W1: fc_d + fc_d^T ; fc_p + fc_p^T
    launch2(GF(t1d, 0, 256, nullptr, 0, 0, 256, dW + (size_t)i * 65536, 1, 256,
               kNF, 256, db + i * 256, nullptr, 0, nullptr, nullptr, fcd, TBd),
            GF(t1p, 0, 256, nullptr, 0, 0, 256, pW + (size_t)i * 65536, 1, 256,
               kNV, 256, pb + i * 256, nullptr, 0, nullptr, nullptr, fcp, TBp));
    // G2: Ad@fc_d + Ap@fc_p
    launch2(GP(AdP, adm, kNF, TBd, kNF, Pd, kNF, kNF, 4),
            GP(ApP, apm, kNV, TBp, kNV, Pp, kNV, kNV, 8));
    // F2
    fin2(FIN(Pd, 4, kNF, 1.f, nullptr, t1d), FIN(Pp, 8, kNV, 1.f, nullptr, t1p));
    // W2: relu(fc+og)+x -> next x (+x^T)
    float* nxd = (i < 2) ? (douts + (size_t)(i + 1) * NFD) : xd3;
    float* nxp = (i < 2) ? (pouts + (size_t)(i + 1) * NVD) : xp3;
    u16* xdT = (i < 2) ? XTd : nullptr;
    u16* xpT = (i < 2) ? XTp : nullptr;
    launch2(GF(t1d, 0, 256, nullptr, 0, 0, 256, dgW + (size_t)i * 65536, 1, 256,
               kNF, 256, dgb + i * 256, fcd, 1, xdc, nxd, nullptr, xdT),
            GF(t1p, 0, 256, nullptr, 0, 0, 256, pgW + (size_t)i * 65536, 1, 256,
               kNV, 256, pgb + i * 256, fcp, 1, xpc, nxp, nullptr, xpT));
    xdc = nxd; xpc = nxp;
  }

  // ---- PDF ----
  face_gather_k<<<dim3(kNF), dim3(256), 0, stream>>>(xp3, xd3, faces, t1d); // f bf16
  tranp(t1d, 0, DIMN, TBd, kNF, kNF, DIMN, nullptr);                        // f^T
  // [out_dual GEMM (192 blk)] + [mapped = A @ f -> Pp (768 blk)] merged
  {
    GJ jo = GF(xd3, 1, 256, t1d, 0, 256, 256, Wd, 1, 512, kNF, 512,
               bd, nullptr, 1, xd3, out1, nullptr, nullptr);
    GJ jm = big ? GP(A16, 0, kNF, TBd, kNF, Pp, kNV, kNF, 8)
                : GP(A, 1, kNF, TBd, kNF, Pp, kNV, kNF, 8);
    launch2(jo, jm);
  }
  fin1(FIN(Pp, 8, kNV, 1.f, nullptr, fcp));                                 // mapped
  // out_primal = relu([x_p, mapped] @ Wp^T + bp) + x_p
  launch1(GF(xp3, 1, 256, fcp, 0, 256, 256, Wp, 1, 512, kNV, 512,
             bp, nullptr, 1, xp3, out0, nullptr, nullptr));
}